// Round 6
// baseline (3422.136 us; speedup 1.0000x reference)
//
#include <hip/hip_runtime.h>
#include <cstdint>
#include <cstddef>

typedef __attribute__((ext_vector_type(4))) float f32x4;
typedef __attribute__((ext_vector_type(8))) short s16x8;
typedef __attribute__((ext_vector_type(4))) unsigned short u16x4;
typedef __attribute__((ext_vector_type(2))) unsigned short u16x2;

#define NLAYER 8
#define DM 1024
#define NTOK 4096
#define DFF2 4096
#define NV 50257
#define NVPAD 50432  // 394*128, for 128-wide LM tiles

__device__ __forceinline__ unsigned short f2bf(float f) {
  unsigned int u = __float_as_uint(f);
  u = u + 0x7fffu + ((u >> 16) & 1u);
  return (unsigned short)(u >> 16);
}

// CK-style generic->AS1/AS3 conversion for global_load_lds (width 16B).
__device__ __forceinline__ void gload_lds16(const void* gp, void* lp) {
  const __attribute__((address_space(1))) unsigned int* g =
      reinterpret_cast<const __attribute__((address_space(1))) unsigned int*>(
          reinterpret_cast<uintptr_t>(gp));
  __attribute__((address_space(3))) unsigned int* l =
      reinterpret_cast<__attribute__((address_space(3))) unsigned int*>(
          (unsigned int)(uintptr_t)lp);
  __builtin_amdgcn_global_load_lds(g, l, 16, 0, 0);
}

// ---------------- weight convert + transpose: out[n][k] = bf16(in[k][n]) ----
__global__ void __launch_bounds__(256) convT_k(const float* __restrict__ in,
                                               unsigned short* __restrict__ out,
                                               int K, int N, size_t zStride) {
  __shared__ float tile[64][65];
  const int n0 = blockIdx.x * 64, k0 = blockIdx.y * 64;
  const float* inp = in + (size_t)blockIdx.z * K * N;
  unsigned short* outp = out + (size_t)blockIdx.z * zStride;
  const int tid = threadIdx.x;
#pragma unroll
  for (int p = 0; p < 16; ++p) {
    const int r = p * 4 + (tid >> 6);
    const int cc = tid & 63;
    const int gn = n0 + cc;
    tile[r][cc] = (gn < N) ? inp[(size_t)(k0 + r) * N + gn] : 0.f;
  }
  __syncthreads();
#pragma unroll
  for (int p = 0; p < 8; ++p) {
    const int lin = p * 256 + tid;
    const int rn = lin >> 5;
    const int c2 = (lin & 31) * 2;
    u16x2 o;
    o[0] = f2bf(tile[c2][rn]);
    o[1] = f2bf(tile[c2 + 1][rn]);
    *(u16x2*)&outp[(size_t)(n0 + rn) * K + k0 + c2] = o;
  }
}

// ---------------- embedding: x = wte[idx] + wpe[t] ----------------
__global__ void __launch_bounds__(256) embed_k(const int* __restrict__ idx,
                                               const float* __restrict__ wte,
                                               const float* __restrict__ wpe,
                                               float* __restrict__ X) {
  const int tok = blockIdx.x;
  const int t = tok & 1023;
  const int id = idx[tok];
  const int c = threadIdx.x * 4;
  f32x4 a = *(const f32x4*)&wte[(size_t)id * DM + c];
  f32x4 p = *(const f32x4*)&wpe[(size_t)t * DM + c];
  a = a + p;
  *(f32x4*)&X[(size_t)tok * DM + c] = a;
}

// ---------------- LayerNorm: f32 in -> bf16 out ----------------
__global__ void __launch_bounds__(256) ln_k(const float* __restrict__ X,
                                            const float* __restrict__ W,
                                            const float* __restrict__ Bp,
                                            unsigned short* __restrict__ O) {
  const int row = blockIdx.x, tid = threadIdx.x;
  const size_t base = (size_t)row * DM;
  f32x4 v = *(const f32x4*)&X[base + tid * 4];
  float s = v[0] + v[1] + v[2] + v[3];
  float q = v[0] * v[0] + v[1] * v[1] + v[2] * v[2] + v[3] * v[3];
#pragma unroll
  for (int m = 1; m < 64; m <<= 1) {
    s += __shfl_xor(s, m);
    q += __shfl_xor(q, m);
  }
  __shared__ float ps[4], pq[4];
  const int wv = tid >> 6;
  if ((tid & 63) == 0) { ps[wv] = s; pq[wv] = q; }
  __syncthreads();
  s = ps[0] + ps[1] + ps[2] + ps[3];
  q = pq[0] + pq[1] + pq[2] + pq[3];
  const float mu = s * (1.f / DM);
  const float var = q * (1.f / DM) - mu * mu;
  const float rstd = rsqrtf(var + 1e-5f);
  f32x4 w = *(const f32x4*)&W[tid * 4];
  f32x4 bb = *(const f32x4*)&Bp[tid * 4];
  u16x4 o;
#pragma unroll
  for (int j = 0; j < 4; ++j) o[j] = f2bf((v[j] - mu) * rstd * w[j] + bb[j]);
  *(u16x4*)&O[base + tid * 4] = o;
}

// -------- fused: X += bias + P0 + P1; then LN(X) -> bf16 O --------
__global__ void __launch_bounds__(256) reduce2ln_k(
    float* __restrict__ X, const float* __restrict__ bias,
    const float* __restrict__ P0, const float* __restrict__ P1,
    const float* __restrict__ W, const float* __restrict__ Bp,
    unsigned short* __restrict__ O) {
  const int row = blockIdx.x, tid = threadIdx.x;
  const size_t base = (size_t)row * DM;
  const size_t i = base + tid * 4;
  f32x4 v = *(f32x4*)&X[i];
  {
    f32x4 b = *(const f32x4*)&bias[tid * 4];
    f32x4 a = *(const f32x4*)&P0[i];
    f32x4 c = *(const f32x4*)&P1[i];
    v = v + b + a + c;
    *(f32x4*)&X[i] = v;
  }
  float s = v[0] + v[1] + v[2] + v[3];
  float q = v[0] * v[0] + v[1] * v[1] + v[2] * v[2] + v[3] * v[3];
#pragma unroll
  for (int m = 1; m < 64; m <<= 1) {
    s += __shfl_xor(s, m);
    q += __shfl_xor(q, m);
  }
  __shared__ float ps[4], pq[4];
  const int wv = tid >> 6;
  if ((tid & 63) == 0) { ps[wv] = s; pq[wv] = q; }
  __syncthreads();
  s = ps[0] + ps[1] + ps[2] + ps[3];
  q = pq[0] + pq[1] + pq[2] + pq[3];
  const float mu = s * (1.f / DM);
  const float var = q * (1.f / DM) - mu * mu;
  const float rstd = rsqrtf(var + 1e-5f);
  f32x4 w = *(const f32x4*)&W[tid * 4];
  f32x4 bb = *(const f32x4*)&Bp[tid * 4];
  u16x4 o;
#pragma unroll
  for (int j = 0; j < 4; ++j) o[j] = f2bf((v[j] - mu) * rstd * w[j] + bb[j]);
  *(u16x4*)&O[base + tid * 4] = o;
}

// ---- GEMM 256x128, 8 waves (4M x 2N), BK=64, ring-3 LDS, phase-paired ----
// Per K-tile t (buf t%3): two phases of
//   {ds_read frags; stage 3 loads of KT(t+2) into buf (t+2)%3;
//    s_barrier; lgkmcnt(0); setprio(1); 16 MFMA; setprio(0); s_barrier}
// Iter boundary: vmcnt(6) (KT(t+1)'s 6 loads are the oldest 6 of 12
// outstanding) -- vmcnt(0) only at t==nt-2. WAR safe: buf (t+2)%3 was last
// read in iter t-1, whose reads completed before its closing barrier.
// XOR swizzle identical to r3 (proven 0-conflict): col-group ^= row&7, via
// pre-swizzled global source + linear gload dest; reads apply the same XOR.
// Optional epilogues: fused V-transpose (cols>=2048 -> vt), nontemporal f32.
__global__ void __launch_bounds__(512, 1) gemm3_k(
    const unsigned short* __restrict__ A, const unsigned short* __restrict__ Bt,
    const float* __restrict__ bias, float* __restrict__ outF,
    unsigned short* __restrict__ outB, unsigned short* __restrict__ vt,
    int M, int N, int K, int lda, int ldc, int relu, int ntStore) {
  __shared__ __align__(16) unsigned short lA[3][256 * 64];
  __shared__ __align__(16) unsigned short lB[3][128 * 64];
  const int tid = threadIdx.x;  // 0..511
  const int wv = tid >> 6, lane = tid & 63;
  const int row0 = blockIdx.y * 256, col0 = blockIdx.x * 128;
  const int wr = wv >> 1, wc = wv & 1;  // 4M x 2N waves; wave tile 64x64

  const int z = blockIdx.z;
  A += (size_t)z * K;
  Bt += (size_t)z * K;
  if (gridDim.z > 1) outF += (size_t)z * M * ldc;

  f32x4 acc[4][4] = {};

  // staging: load l covers rows l*64 + (tid>>3); source col-group pre-swizzled
  const int sColSw = (((tid & 7) ^ ((tid >> 3) & 7))) * 8;
  const unsigned short* gA = A + (size_t)(row0 + (tid >> 3)) * lda + sColSw;
  const unsigned short* gB = Bt + (size_t)(col0 + (tid >> 3)) * lda + sColSw;
  const size_t step64 = (size_t)64 * lda;

  const int rbase = lane & 15;
  const int kSw = (lane & 7) * 8;
  const int g8 = (lane >> 4) * 8;

  const int nt = K >> 6;

#define STGA(t, l) \
  gload_lds16(gA + (size_t)(t) * 64 + (l) * step64, &lA[(t) % 3][(l) * 4096 + tid * 8])
#define STGB(t, l) \
  gload_lds16(gB + (size_t)(t) * 64 + (l) * step64, &lB[(t) % 3][(l) * 4096 + tid * 8])

  // prologue: stage KT0, KT1 (12 loads); wait KT0 (oldest 6)
  STGA(0, 0); STGA(0, 1); STGA(0, 2); STGA(0, 3); STGB(0, 0); STGB(0, 1);
  STGA(1, 0); STGA(1, 1); STGA(1, 2); STGA(1, 3); STGB(1, 0); STGB(1, 1);
  asm volatile("s_waitcnt vmcnt(6)" ::: "memory");
  __builtin_amdgcn_s_barrier();

  for (int t = 0; t < nt; ++t) {
    const unsigned short* la = &lA[t % 3][0];
    const unsigned short* lb = &lB[t % 3][0];
    const bool stg = (t + 2 < nt);
    s16x8 af[4][2], bf[2][2];
    // ---- phase 0: A frags (kept both phases) + B frags n=0,1 ----
#pragma unroll
    for (int ks = 0; ks < 2; ++ks) {
      const int kph = (ks * 32 + g8) ^ kSw;
#pragma unroll
      for (int m = 0; m < 4; ++m)
        af[m][ks] = *(const s16x8*)&la[(wr * 64 + m * 16 + rbase) * 64 + kph];
#pragma unroll
      for (int n = 0; n < 2; ++n)
        bf[n][ks] = *(const s16x8*)&lb[(wc * 64 + n * 16 + rbase) * 64 + kph];
    }
    if (stg) { STGA(t + 2, 0); STGA(t + 2, 1); STGA(t + 2, 2); }
    __builtin_amdgcn_s_barrier();
    asm volatile("s_waitcnt lgkmcnt(0)" ::: "memory");
    __builtin_amdgcn_s_setprio(1);
#pragma unroll
    for (int m = 0; m < 4; ++m)
#pragma unroll
      for (int n = 0; n < 2; ++n)
#pragma unroll
        for (int ks = 0; ks < 2; ++ks)
          acc[m][n] = __builtin_amdgcn_mfma_f32_16x16x32_bf16(
              af[m][ks], bf[n][ks], acc[m][n], 0, 0, 0);
    __builtin_amdgcn_s_setprio(0);
    __builtin_amdgcn_s_barrier();
    // ---- phase 1: B frags n=2,3 ----
#pragma unroll
    for (int ks = 0; ks < 2; ++ks) {
      const int kph = (ks * 32 + g8) ^ kSw;
#pragma unroll
      for (int n = 0; n < 2; ++n)
        bf[n][ks] =
            *(const s16x8*)&lb[(wc * 64 + 32 + n * 16 + rbase) * 64 + kph];
    }
    if (stg) { STGA(t + 2, 3); STGB(t + 2, 0); STGB(t + 2, 1); }
    __builtin_amdgcn_s_barrier();
    asm volatile("s_waitcnt lgkmcnt(0)" ::: "memory");
    __builtin_amdgcn_s_setprio(1);
#pragma unroll
    for (int m = 0; m < 4; ++m)
#pragma unroll
      for (int n = 0; n < 2; ++n)
#pragma unroll
        for (int ks = 0; ks < 2; ++ks)
          acc[m][2 + n] = __builtin_amdgcn_mfma_f32_16x16x32_bf16(
              af[m][ks], bf[n][ks], acc[m][2 + n], 0, 0, 0);
    __builtin_amdgcn_s_setprio(0);
    // ---- iter boundary: KT(t+1) must be landed ----
    if (t + 1 < nt) {
      if (stg)
        asm volatile("s_waitcnt vmcnt(6)" ::: "memory");
      else
        asm volatile("s_waitcnt vmcnt(0)" ::: "memory");
    }
    __builtin_amdgcn_s_barrier();
  }
#undef STGA
#undef STGB

  const int baseRow = row0 + wr * 64 + ((lane >> 4) * 4);
  const int baseCol = col0 + wc * 64 + rbase;
#pragma unroll
  for (int m = 0; m < 4; ++m) {
#pragma unroll
    for (int n = 0; n < 4; ++n) {
      const int colc = baseCol + n * 16;
      if (colc < N) {
        const int rowc0 = baseRow + m * 16;
        if (vt && colc >= 2048) {
          // fused V-transpose: Vt[(b*16+h)*64+hs][t], 4 consecutive t per lane
          const int f = colc - 2048;
          const int b = rowc0 >> 10, t0 = rowc0 & 1023;
          u16x4 o;
#pragma unroll
          for (int r = 0; r < 4; ++r) o[r] = f2bf(acc[m][n][r]);
          *(u16x4*)&vt[((size_t)((b << 4) + (f >> 6)) * 64 + (f & 63)) * 1024 + t0] = o;
        } else {
          const float bv = bias ? bias[colc] : 0.f;
#pragma unroll
          for (int r = 0; r < 4; ++r) {
            float v = acc[m][n][r] + bv;
            if (relu) v = fmaxf(v, 0.f);
            if (outF) {
              if (ntStore)
                __builtin_nontemporal_store(v, &outF[(size_t)(rowc0 + r) * ldc + colc]);
              else
                outF[(size_t)(rowc0 + r) * ldc + colc] = v;
            }
            if (outB) outB[(size_t)(rowc0 + r) * ldc + colc] = f2bf(v);
          }
        }
      }
    }
  }
}

// ---------------- fused causal attention (flash-style) ----------------
__global__ void __launch_bounds__(256) attn_k(const unsigned short* __restrict__ Q,
                                              const unsigned short* __restrict__ Kb,
                                              const unsigned short* __restrict__ Vt,
                                              unsigned short* __restrict__ O,
                                              int ldq) {
  const int qt = blockIdx.x;
  const int bh = blockIdx.y;
  const int b = bh >> 4, h = bh & 15;
  const int tid = threadIdx.x, wv = tid >> 6, lane = tid & 63;
  const int g = lane >> 4, c = lane & 15;
  __shared__ __align__(16) unsigned short lP[4][16 * 64];
  const int qw0 = qt * 64 + wv * 16;
  s16x8 qf0, qf1;
  {
    const size_t qoff = ((size_t)(b * 1024 + qw0 + c)) * ldq + h * 64 + g * 8;
    qf0 = *(const s16x8*)&Q[qoff];
    qf1 = *(const s16x8*)&Q[qoff + 32];
  }
  f32x4 acc[4] = {};
  float mrun[4], lrun[4];
#pragma unroll
  for (int r = 0; r < 4; ++r) { mrun[r] = -1e30f; lrun[r] = 0.f; }

  for (int kt = 0; kt <= qt; ++kt) {
    f32x4 s[4] = {};
#pragma unroll
    for (int n = 0; n < 4; ++n) {
      const size_t koff = ((size_t)(b * 1024 + kt * 64 + n * 16 + c)) * ldq + h * 64 + g * 8;
      s16x8 k0 = *(const s16x8*)&Kb[koff];
      s16x8 k1 = *(const s16x8*)&Kb[koff + 32];
      s[n] = __builtin_amdgcn_mfma_f32_16x16x32_bf16(qf0, k0, s[n], 0, 0, 0);
      s[n] = __builtin_amdgcn_mfma_f32_16x16x32_bf16(qf1, k1, s[n], 0, 0, 0);
    }
    float p[4][4], mx[4] = {-1e30f, -1e30f, -1e30f, -1e30f};
#pragma unroll
    for (int n = 0; n < 4; ++n)
#pragma unroll
      for (int r = 0; r < 4; ++r) {
        const int qrow = qw0 + g * 4 + r;
        const int key = kt * 64 + n * 16 + c;
        float v = s[n][r] * 0.125f;
        if (key > qrow) v = -1e30f;
        p[n][r] = v;
        mx[r] = fmaxf(mx[r], v);
      }
#pragma unroll
    for (int r = 0; r < 4; ++r)
#pragma unroll
      for (int m = 1; m <= 8; m <<= 1) mx[r] = fmaxf(mx[r], __shfl_xor(mx[r], m));
    float al[4], rs[4];
#pragma unroll
    for (int r = 0; r < 4; ++r) {
      const float mn = fmaxf(mrun[r], mx[r]);
      al[r] = __expf(mrun[r] - mn);
      mrun[r] = mn;
      rs[r] = 0.f;
    }
#pragma unroll
    for (int n = 0; n < 4; ++n)
#pragma unroll
      for (int r = 0; r < 4; ++r) {
        const float e = __expf(p[n][r] - mrun[r]);
        p[n][r] = e;
        rs[r] += e;
      }
#pragma unroll
    for (int r = 0; r < 4; ++r) {
#pragma unroll
      for (int m = 1; m <= 8; m <<= 1) rs[r] += __shfl_xor(rs[r], m);
      lrun[r] = lrun[r] * al[r] + rs[r];
    }
#pragma unroll
    for (int n = 0; n < 4; ++n)
#pragma unroll
      for (int r = 0; r < 4; ++r) acc[n][r] *= al[r];
    __syncthreads();
#pragma unroll
    for (int n = 0; n < 4; ++n)
#pragma unroll
      for (int r = 0; r < 4; ++r)
        lP[wv][(g * 4 + r) * 64 + n * 16 + c] = f2bf(p[n][r]);
    __syncthreads();
    s16x8 pa0 = *(const s16x8*)&lP[wv][c * 64 + g * 8];
    s16x8 pa1 = *(const s16x8*)&lP[wv][c * 64 + 32 + g * 8];
#pragma unroll
    for (int n = 0; n < 4; ++n) {
      const size_t voff = ((size_t)(bh * 64 + n * 16 + c)) * 1024 + kt * 64 + g * 8;
      s16x8 v0 = *(const s16x8*)&Vt[voff];
      s16x8 v1 = *(const s16x8*)&Vt[voff + 32];
      acc[n] = __builtin_amdgcn_mfma_f32_16x16x32_bf16(pa0, v0, acc[n], 0, 0, 0);
      acc[n] = __builtin_amdgcn_mfma_f32_16x16x32_bf16(pa1, v1, acc[n], 0, 0, 0);
    }
  }
#pragma unroll
  for (int n = 0; n < 4; ++n)
#pragma unroll
    for (int r = 0; r < 4; ++r) {
      const size_t row = (size_t)(b * 1024 + qw0 + g * 4 + r);
      O[row * DM + h * 64 + n * 16 + c] = f2bf(acc[n][r] / lrun[r]);
    }
}

// ---------------- host ----------------
extern "C" void kernel_launch(void* const* d_in, const int* in_sizes, int n_in,
                              void* d_out, int out_size, void* d_ws, size_t ws_size,
                              hipStream_t stream) {
  const int* idx = (const int*)d_in[0];
  const float* wte = (const float*)d_in[1];
  const float* wpe = (const float*)d_in[2];
  const float* wq = (const float*)d_in[3];
  const float* wk = (const float*)d_in[4];
  const float* wv = (const float*)d_in[5];
  const float* wo = (const float*)d_in[6];
  const float* bo = (const float*)d_in[7];
  const float* ln1w = (const float*)d_in[8];
  const float* ln1b = (const float*)d_in[9];
  const float* ln2w = (const float*)d_in[10];
  const float* ln2b = (const float*)d_in[11];
  const float* w1 = (const float*)d_in[12];
  const float* b1 = (const float*)d_in[13];
  const float* w2 = (const float*)d_in[14];
  const float* b2 = (const float*)d_in[15];
  const float* lnfw = (const float*)d_in[16];
  const float* lnfb = (const float*)d_in[17];
  const float* wlm = (const float*)d_in[18];
  const float* blm = (const float*)d_in[19];
  float* out = (float*)d_out;

  char* ws = (char*)d_ws;
  size_t off = 0;
  auto alloc = [&](size_t bytes) -> void* {
    void* p = ws + off;
    off += (bytes + 255) & ~(size_t)255;
    return p;
  };
  unsigned short* wqkvT = (unsigned short*)alloc((size_t)NLAYER * 3072 * DM * 2);  // 48MB
  unsigned short* woT = (unsigned short*)alloc((size_t)NLAYER * DM * DM * 2);      // 16MB
  unsigned short* w1T = (unsigned short*)alloc((size_t)NLAYER * DM * DFF2 * 2);    // 64MB
  unsigned short* w2T = (unsigned short*)alloc((size_t)NLAYER * DM * DFF2 * 2);    // 64MB
  // wlmT aliases w1T+w2T (dead after layer loop): 50432*1024*2 = 103MB <= 128MB
  unsigned short* wlmT = w1T;
  float* X = (float*)alloc((size_t)NTOK * DM * 4);                                 // 16MB
  unsigned short* Hb = (unsigned short*)alloc((size_t)NTOK * DM * 2);              // 8MB
  // union region 32MB: {QKVb 24MB + Ab 8MB} early, {P0 16MB + P1 16MB} at w2
  char* uni = (char*)alloc((size_t)32 * 1024 * 1024);
  unsigned short* QKVb = (unsigned short*)uni;
  unsigned short* Ab = (unsigned short*)(uni + (size_t)24 * 1024 * 1024);
  float* P0 = (float*)uni;
  float* P1 = (float*)(uni + (size_t)16 * 1024 * 1024);
  unsigned short* VtB = (unsigned short*)alloc((size_t)NTOK * DM * 2);             // 8MB
  unsigned short* Mid = (unsigned short*)alloc((size_t)NTOK * DFF2 * 2);           // 32MB
  float* MidF = (float*)Mid;

  const size_t qkvStride = (size_t)3072 * DM;
  convT_k<<<dim3(16, 16, 8), 256, 0, stream>>>(wq, wqkvT, DM, DM, qkvStride);
  convT_k<<<dim3(16, 16, 8), 256, 0, stream>>>(wk, wqkvT + (size_t)1024 * DM, DM, DM, qkvStride);
  convT_k<<<dim3(16, 16, 8), 256, 0, stream>>>(wv, wqkvT + (size_t)2048 * DM, DM, DM, qkvStride);
  convT_k<<<dim3(16, 16, 8), 256, 0, stream>>>(wo, woT, DM, DM, (size_t)DM * DM);
  convT_k<<<dim3(64, 16, 8), 256, 0, stream>>>(w1, w1T, DM, DFF2, (size_t)DM * DFF2);
  convT_k<<<dim3(16, 64, 8), 256, 0, stream>>>(w2, w2T, DFF2, DM, (size_t)DM * DFF2);

  embed_k<<<dim3(NTOK), 256, 0, stream>>>(idx, wte, wpe, X);
  ln_k<<<dim3(NTOK), 256, 0, stream>>>(X, ln1w, ln1b, Hb);  // layer-0 ln1

  for (int i = 0; i < NLAYER; ++i) {
    const size_t wOff = (size_t)i * DM * DM;
    const size_t fOff = (size_t)i * DM * DFF2;
    // fused QKV with V-transpose epilogue (V cols -> VtB)
    gemm3_k<<<dim3(24, 16), 512, 0, stream>>>(Hb, wqkvT + i * qkvStride, nullptr,
                                              nullptr, QKVb, VtB, NTOK, 3072, DM,
                                              DM, 3072, 0, 0);
    attn_k<<<dim3(16, 64), 256, 0, stream>>>(QKVb, QKVb + 1024, VtB, Ab, 3072);
    // wo: split-K=2 (K=512 each), partials into MidF (dead here)
    gemm3_k<<<dim3(8, 16, 2), 512, 0, stream>>>(Ab, woT + wOff, nullptr, MidF,
                                                nullptr, nullptr, NTOK, DM,
                                                DM / 2, DM, DM, 0, 0);
    reduce2ln_k<<<dim3(NTOK), 256, 0, stream>>>(X, bo + i * DM, MidF,
                                                MidF + (size_t)NTOK * DM,
                                                ln2w + i * DM, ln2b + i * DM, Hb);
    // w1: relu, bf16 out
    gemm3_k<<<dim3(32, 16), 512, 0, stream>>>(Hb, w1T + fOff, b1 + i * DFF2,
                                              nullptr, Mid, nullptr, NTOK, DFF2,
                                              DM, DM, DFF2, 1, 0);
    // w2: split-K=2 (K=2048 each), partials P0/P1 (union region, free)
    gemm3_k<<<dim3(8, 16, 2), 512, 0, stream>>>(Mid, w2T + fOff, nullptr, P0,
                                                nullptr, nullptr, NTOK, DM,
                                                DFF2 / 2, DFF2, DM, 0, 0);
    const float* nw = (i < NLAYER - 1) ? ln1w + (i + 1) * DM : lnfw;
    const float* nb = (i < NLAYER - 1) ? ln1b + (i + 1) * DM : lnfb;
    reduce2ln_k<<<dim3(NTOK), 256, 0, stream>>>(X, b2 + i * DM, P0, P1, nw, nb, Hb);
  }

  // LM head: convert wlm (padded to 50432 rows, aliases dead w1T/w2T), big GEMM
  // with nontemporal logits stores (keep B panel L3-resident).
  convT_k<<<dim3(788, 16, 1), 256, 0, stream>>>(wlm, wlmT, DM, NV, 0);
  gemm3_k<<<dim3(394, 16), 512, 0, stream>>>(Hb, wlmT, blm, out, nullptr, nullptr,
                                             NTOK, NV, DM, DM, NV, 0, 1);
}